// Round 3
// baseline (910.654 us; speedup 1.0000x reference)
//
#include <hip/hip_runtime.h>
#include <stdint.h>

typedef unsigned short u16;
typedef unsigned int u32;
typedef __attribute__((ext_vector_type(8))) short s16x8;   // 8 bf16 (4 VGPRs) MFMA frag
typedef __attribute__((ext_vector_type(4))) float f32x4;   // MFMA accum / vec4

// ---------- bf16 helpers ----------
__device__ __forceinline__ u16 f2bf(float f) {
  union { float f; u32 u; } v; v.f = f;
  u32 u = v.u;
  return (u16)((u + 0x7fffu + ((u >> 16) & 1u)) >> 16);
}
__device__ __forceinline__ float bf2f_lo(u32 u) {
  union { u32 uu; float f; } v; v.uu = u << 16; return v.f;
}
__device__ __forceinline__ float bf2f_hi(u32 u) {
  union { u32 uu; float f; } v; v.uu = u & 0xffff0000u; return v.f;
}
__device__ __forceinline__ void cvt8(uint4 w, float* f) {
  f[0] = bf2f_lo(w.x); f[1] = bf2f_hi(w.x);
  f[2] = bf2f_lo(w.y); f[3] = bf2f_hi(w.y);
  f[4] = bf2f_lo(w.z); f[5] = bf2f_hi(w.z);
  f[6] = bf2f_lo(w.w); f[7] = bf2f_hi(w.w);
}

// ---------- constants ----------
#define NT 49        // tokens per window
#define CD 256       // dim
#define NWIN 4096    // 64 imgs * 64 windows
#define NBLK 256     // persistent blocks (1 per CU)
#define WPB 16       // windows per block
#define SB_RS 520    // q|k bf16 row stride
#define SX_RS 264    // x / attn-out bf16 row stride
#define SVT_RS 72    // V^T kv stride

// LDS offsets (bytes)
#define L_SX  0                      // [64][264] bf16 = 33792
#define L_SB  33792                  // [64][520] bf16 = 66560
#define L_SVT 100352                 // [256][72] bf16 = 36864
#define L_SRQ 137216
#define L_SRK 139264
#define L_SINV 141312
#define L_TOTAL 143360

// workspace offsets (bytes)
#define WS_BIASC 8192                 // 4*8*64*64 f32 = 524288
#define WS_WQKV  (8192 + 524288)      // 532480: 384 KB
#define WS_WPROJ (532480 + 393216)    // 925696: 128 KB

// =====================================================================
// Kernel A: CPB MLP: table[p*8+h]
// =====================================================================
__global__ void cpb_table_kernel(const float* __restrict__ coords,
                                 const float* __restrict__ w1,
                                 const float* __restrict__ b1,
                                 const float* __restrict__ w2,
                                 float* __restrict__ table) {
  int t = blockIdx.x * 256 + threadIdx.x;
  if (t >= 169 * 8) return;
  int p = t >> 3, h = t & 7;
  float c0 = coords[p * 2], c1 = coords[p * 2 + 1];
  float acc = 0.f;
  for (int j = 0; j < 512; ++j) {
    float hid = fmaf(c0, w1[j * 2], fmaf(c1, w1[j * 2 + 1], b1[j]));
    hid = fmaxf(hid, 0.f);
    acc = fmaf(hid, w2[h * 512 + j], acc);
  }
  table[t] = acc;
}

// =====================================================================
// Kernel B: combined bias table, 4 mask types (interior/right/bottom/corner)
//   biasC[t][h][q][kv] = rpb(h,q,kv) + mask[type_rep(t)][q][kv]; pads -> -1e9
// =====================================================================
__global__ void biasc_prep(const float* __restrict__ table,
                           const int* __restrict__ rpi,
                           const float* __restrict__ mask,
                           float* __restrict__ biasC) {
  int idx = blockIdx.x * 256 + threadIdx.x;
  if (idx >= 4 * 8 * 4096) return;
  int t = idx >> 15;
  int h = (idx >> 12) & 7;
  int q = (idx >> 6) & 63;
  int kv = idx & 63;
  float v = -1e9f;
  if (q < 49 && kv < 49) {
    float tb = table[rpi[q * 49 + kv] * 8 + h];
    float rpb = 16.f / (1.f + __expf(-tb));
    int wimg = ((t & 2) ? 56 : 0) + ((t & 1) ? 7 : 0);
    v = rpb + mask[wimg * 2401 + q * 49 + kv];
  }
  biasC[idx] = v;
}

// =====================================================================
// Kernel C: weights f32 -> bf16, MFMA fragment order.
// frag[ntile][kk][lane][8]; value = W[nt*16+(l&15)][kk*32+(l>>4)*8+j]
// =====================================================================
__global__ void wcvt_kernel(const float* __restrict__ qkv_w,
                            const float* __restrict__ proj_w,
                            u16* __restrict__ wq, u16* __restrict__ wp) {
  int t = blockIdx.x * 256 + threadIdx.x;
  if (t >= 32768) return;
  const float* src; u16* dst; int idx;
  if (t < 24576) { idx = t; src = qkv_w; dst = wq + (size_t)idx * 8; }
  else           { idx = t - 24576; src = proj_w; dst = wp + (size_t)idx * 8; }
  int nt = idx >> 9, rem = idx & 511;
  int kk = rem >> 6, l = rem & 63;
  int n = nt * 16 + (l & 15);
  int k = kk * 32 + (l >> 4) * 8;
  const float4* s = (const float4*)(src + (size_t)n * 256 + k);
  float4 v0 = s[0], v1 = s[1];
  u32 w0 = (u32)f2bf(v0.x) | ((u32)f2bf(v0.y) << 16);
  u32 w1 = (u32)f2bf(v0.z) | ((u32)f2bf(v0.w) << 16);
  u32 w2 = (u32)f2bf(v1.x) | ((u32)f2bf(v1.y) << 16);
  u32 w3 = (u32)f2bf(v1.z) | ((u32)f2bf(v1.w) << 16);
  *(uint4*)dst = make_uint4(w0, w1, w2, w3);
}

// =====================================================================
// P2 body: qkv GEMM. First V0 tiles are q/k (swapped mfma -> packed col
// stores), rest are v (unswapped -> V^T packed stores). V0 per wave:
// hh<5 -> 6, hh==5 -> 2, hh>=6 -> 0.
// =====================================================================
template<int V0>
__device__ __forceinline__ void p2_body(
    const u16* sX, u16* sB, u16* sVT, const u16* wqb,
    const float* __restrict__ q_bias, const float* __restrict__ v_bias,
    const int hh, const int lr, const int lg) {
  f32x4 acc[6][4];
#pragma unroll
  for (int nt = 0; nt < 6; ++nt)
#pragma unroll
    for (int mt = 0; mt < 4; ++mt) acc[nt][mt] = (f32x4){0.f, 0.f, 0.f, 0.f};
#pragma unroll 2
  for (int kk = 0; kk < 8; ++kk) {
    s16x8 a[4], b[6];
#pragma unroll
    for (int mt = 0; mt < 4; ++mt)
      a[mt] = *(const s16x8*)&sX[(mt * 16 + lr) * SX_RS + kk * 32 + lg * 8];
#pragma unroll
    for (int nt = 0; nt < 6; ++nt)
      b[nt] = *(const s16x8*)&wqb[(nt * 8 + kk) * 512];
#pragma unroll
    for (int nt = 0; nt < 6; ++nt)
#pragma unroll
      for (int mt = 0; mt < 4; ++mt)
        acc[nt][mt] = (nt < V0)
            ? __builtin_amdgcn_mfma_f32_16x16x32_bf16(b[nt], a[mt], acc[nt][mt], 0, 0, 0)
            : __builtin_amdgcn_mfma_f32_16x16x32_bf16(a[mt], b[nt], acc[nt][mt], 0, 0, 0);
  }
#pragma unroll
  for (int nt = 0; nt < 6; ++nt) {
    const int n0 = hh * 96 + nt * 16;
    if (nt < V0) {
      // q/k swapped: lane holds token=16mt+lr, 4 consecutive cols (n0&255)+4lg+i
      const int r = n0 >> 8;               // 0=q, 1=k (wave-uniform)
      const int cb = (n0 & 255) + 4 * lg;
      float4 bq = make_float4(0.f, 0.f, 0.f, 0.f);
      if (r == 0) bq = *(const float4*)(q_bias + cb);
      const int coff = (r << 8) + cb;
#pragma unroll
      for (int mt = 0; mt < 4; ++mt) {
        const int token = mt * 16 + lr;
        if (token < NT) {
          uint2 pk;
          pk.x = (u32)f2bf(acc[nt][mt][0] + bq.x) | ((u32)f2bf(acc[nt][mt][1] + bq.y) << 16);
          pk.y = (u32)f2bf(acc[nt][mt][2] + bq.z) | ((u32)f2bf(acc[nt][mt][3] + bq.w) << 16);
          *(uint2*)&sB[token * SB_RS + coff] = pk;
        }
      }
    } else {
      // v unswapped: lane holds col d=(n0&255)+lr, rows token=16mt+4lg+i
      const int c0 = (n0 & 255) + lr;
      const float bv = v_bias[c0];
      u16* vtb = &sVT[c0 * SVT_RS];
#pragma unroll
      for (int mt = 0; mt < 4; ++mt) {
        const int row0 = mt * 16 + lg * 4;
        float v0 = acc[nt][mt][0] + bv, v1 = acc[nt][mt][1] + bv;
        float v2 = acc[nt][mt][2] + bv, v3 = acc[nt][mt][3] + bv;
        if (mt < 3) {
          uint2 pk2;
          pk2.x = (u32)f2bf(v0) | ((u32)f2bf(v1) << 16);
          pk2.y = (u32)f2bf(v2) | ((u32)f2bf(v3) << 16);
          *(uint2*)&vtb[row0] = pk2;
        } else {
          if (row0     < NT) vtb[row0]     = f2bf(v0);
          if (row0 + 1 < NT) vtb[row0 + 1] = f2bf(v1);
          if (row0 + 2 < NT) vtb[row0 + 2] = f2bf(v2);
          if (row0 + 3 < NT) vtb[row0 + 3] = f2bf(v3);
        }
      }
    }
  }
}

// =====================================================================
// Persistent fused kernel: 256 blocks x 16 windows, x prefetch in regs,
// proj weights cached in regs, biasC 4-type table.
// =====================================================================
__global__ __launch_bounds__(512, 2) void swin_fused(
    const float* __restrict__ x,
    const float* __restrict__ q_bias, const float* __restrict__ v_bias,
    const float* __restrict__ logit_scale, const float* __restrict__ biasC,
    const u16* __restrict__ wq, const u16* __restrict__ wp,
    const float* __restrict__ proj_b,
    float* __restrict__ out) {
  __shared__ __attribute__((aligned(16))) unsigned char smem[L_TOTAL];
  u16*   sX  = (u16*)(smem + L_SX);
  u16*   sB  = (u16*)(smem + L_SB);
  u16*   sVT = (u16*)(smem + L_SVT);
  float* sRQ = (float*)(smem + L_SRQ);
  float* sRK = (float*)(smem + L_SRK);
  float* sINV= (float*)(smem + L_SINV);

  const int tid = threadIdx.x;
  const int hh = tid >> 6;   // wave / head
  const int il = tid & 63;   // lane
  const int lr = il & 15;
  const int lg = il >> 4;
  const int wbase = blockIdx.x * WPB;

  // ---- prologue: cache proj weights + bias in regs; scl; zero LDS pads ----
  s16x8 wpr[2][8];
  {
    const u16* wpb = wp + (size_t)hh * 8192 + il * 8;
#pragma unroll
    for (int nt = 0; nt < 2; ++nt)
#pragma unroll
      for (int kk = 0; kk < 8; ++kk)
        wpr[nt][kk] = *(const s16x8*)&wpb[(nt * 8 + kk) * 512];
  }
  float4 pb4[2];
#pragma unroll
  for (int nt = 0; nt < 2; ++nt)
    pb4[nt] = *(const float4*)(proj_b + hh * 32 + nt * 16 + 4 * lg);
  const float scl = __expf(fminf(logit_scale[hh], 4.605170186f));

  {
    u32* zx = (u32*)&sX[49 * SX_RS];     // 15*264/2
    for (int e = tid; e < 1980; e += 512) zx[e] = 0;
    u32* zb = (u32*)&sB[49 * SB_RS];     // 15*520/2
    for (int e = tid; e < 3900; e += 512) zb[e] = 0;
    u32* zv = (u32*)sVT;                 // 256*72/2
    for (int e = tid; e < 9216; e += 512) zv[e] = 0;
  }

  // x prefetch registers
  float4 xr[6]; float4 xr6;
  auto loadx = [&](int w) {
    const float4* xg = (const float4*)(x + (size_t)w * (NT * CD));
#pragma unroll
    for (int i = 0; i < 6; ++i) xr[i] = xg[tid + 512 * i];
    if (tid < 64) xr6 = xg[3072 + tid];
  };
  auto storex = [&]() {
#pragma unroll
    for (int i = 0; i < 6; ++i) {
      const int e = tid + 512 * i;
      const int row = e >> 6, c4 = e & 63;
      float4 v = xr[i];
      u32 w0 = (u32)f2bf(v.x) | ((u32)f2bf(v.y) << 16);
      u32 w1 = (u32)f2bf(v.z) | ((u32)f2bf(v.w) << 16);
      *(uint2*)&sX[row * SX_RS + c4 * 4] = make_uint2(w0, w1);
    }
    if (tid < 64) {
      const int e = 3072 + tid;
      const int row = e >> 6, c4 = e & 63;
      float4 v = xr6;
      u32 w0 = (u32)f2bf(v.x) | ((u32)f2bf(v.y) << 16);
      u32 w1 = (u32)f2bf(v.z) | ((u32)f2bf(v.w) << 16);
      *(uint2*)&sX[row * SX_RS + c4 * 4] = make_uint2(w0, w1);
    }
  };

  loadx(wbase);
  storex();
  __syncthreads();

  for (int t = 0; t < WPB; ++t) {
    const int wid = wbase + t;
    const int wimg = wid & 63;

    // ---- P2: qkv via MFMA ----
    {
      const u16* wqb = wq + (size_t)hh * 24576 + il * 8;
      if (hh < 5)       p2_body<6>(sX, sB, sVT, wqb, q_bias, v_bias, hh, lr, lg);
      else if (hh == 5) p2_body<2>(sX, sB, sVT, wqb, q_bias, v_bias, hh, lr, lg);
      else              p2_body<0>(sX, sB, sVT, wqb, q_bias, v_bias, hh, lr, lg);
    }
    __syncthreads();

    // ---- P3a: per-row inverse norms (rot breaks 8-way bank conflict) ----
    {
      float rqs = 0.f, rkv = 0.f;
      if (il < NT) {
        const uint4* qb4 = (const uint4*)&sB[il * SB_RS + hh * 32];
        const uint4* kb4 = (const uint4*)&sB[il * SB_RS + 256 + hh * 32];
        const int rot = (il >> 3) & 3;
        float f[8];
        float sq = 1e-6f, sk = 1e-6f;
#pragma unroll
        for (int c = 0; c < 4; ++c) {
          const int cg = (c + rot) & 3;
          cvt8(qb4[cg], f);
#pragma unroll
          for (int j = 0; j < 8; ++j) sq = fmaf(f[j], f[j], sq);
        }
#pragma unroll
        for (int c = 0; c < 4; ++c) {
          const int cg = (c + rot) & 3;
          cvt8(kb4[cg], f);
#pragma unroll
          for (int j = 0; j < 8; ++j) sk = fmaf(f[j], f[j], sk);
        }
        rqs = rsqrtf(sq) * scl;
        rkv = rsqrtf(sk);
      }
      sRQ[hh * 64 + il] = rqs;   // pad rows -> 0 (kills pad kv columns)
      sRK[hh * 64 + il] = rkv;
    }
    __syncthreads();

    // ---- P3b/c: S^T MFMA -> softmax -> PV MFMA (swapped) ----
    {
      const int h = hh;
      const int type = (((wimg >> 3) == 7) ? 2 : 0) | (((wimg & 7) == 7) ? 1 : 0);
      const float* bp = biasC + ((size_t)(type * 8 + h) << 12);
      f32x4 bias[4][4];
#pragma unroll
      for (int nt = 0; nt < 4; ++nt)
#pragma unroll
        for (int mt = 0; mt < 4; ++mt)
          bias[nt][mt] = *(const f32x4*)(bp + (lr + 16 * nt) * 64 + 16 * mt + 4 * lg);
      // S^T = mfma(k, q): row=kv, col=q
      s16x8 ka[4], qb[4];
#pragma unroll
      for (int mt = 0; mt < 4; ++mt)
        ka[mt] = *(const s16x8*)&sB[(lr + 16 * mt) * SB_RS + 256 + h * 32 + lg * 8];
#pragma unroll
      for (int nt = 0; nt < 4; ++nt)
        qb[nt] = *(const s16x8*)&sB[(lr + 16 * nt) * SB_RS + h * 32 + lg * 8];
      f32x4 sacc[4][4];
#pragma unroll
      for (int nt = 0; nt < 4; ++nt)
#pragma unroll
        for (int mt = 0; mt < 4; ++mt)
          sacc[nt][mt] = __builtin_amdgcn_mfma_f32_16x16x32_bf16(
              ka[mt], qb[nt], (f32x4){0.f, 0.f, 0.f, 0.f}, 0, 0, 0);
      f32x4 rk4[4];
#pragma unroll
      for (int mt = 0; mt < 4; ++mt)
        rk4[mt] = *(const f32x4*)&sRK[h * 64 + 16 * mt + 4 * lg];
#pragma unroll
      for (int nt = 0; nt < 4; ++nt) {
        const float rq_ = sRQ[h * 64 + lr + 16 * nt];
        float mx = -3e38f;
#pragma unroll
        for (int mt = 0; mt < 4; ++mt)
#pragma unroll
          for (int i = 0; i < 4; ++i) {
            float tv = fmaf(sacc[nt][mt][i] * rk4[mt][i], rq_, bias[nt][mt][i]);
            sacc[nt][mt][i] = tv;
            mx = fmaxf(mx, tv);
          }
        mx = fmaxf(mx, __shfl_xor(mx, 16, 64));
        mx = fmaxf(mx, __shfl_xor(mx, 32, 64));
        float sm = 0.f;
#pragma unroll
        for (int mt = 0; mt < 4; ++mt)
#pragma unroll
          for (int i = 0; i < 4; ++i) {
            float e = __expf(sacc[nt][mt][i] - mx);
            sacc[nt][mt][i] = e;
            sm += e;
          }
        sm += __shfl_xor(sm, 16, 64);
        sm += __shfl_xor(sm, 32, 64);
        if (lg == 0) sINV[h * 64 + lr + 16 * nt] = 1.0f / sm;
      }
      // pack P to bf16 pairs
      u32 pkk[4][4][2];
#pragma unroll
      for (int nt = 0; nt < 4; ++nt)
#pragma unroll
        for (int mt = 0; mt < 4; ++mt) {
          pkk[nt][mt][0] = (u32)f2bf(sacc[nt][mt][0]) | ((u32)f2bf(sacc[nt][mt][1]) << 16);
          pkk[nt][mt][1] = (u32)f2bf(sacc[nt][mt][2]) | ((u32)f2bf(sacc[nt][mt][3]) << 16);
        }
      // V^T B-frags
      s16x8 vb[2][2];
#pragma unroll
      for (int nd = 0; nd < 2; ++nd)
#pragma unroll
        for (int s = 0; s < 2; ++s)
          vb[nd][s] = *(const s16x8*)&sVT[(h * 32 + nd * 16 + lr) * SVT_RS + lg * 8 + 32 * s];
      // redistribute P into A-frag order via shfl
      const int srcA = lr + ((il & 16) << 1);
      const int srcB = srcA + 16;
      const bool gh = (il & 32) != 0;
      f32x4 oacc[4][2];
#pragma unroll
      for (int mo = 0; mo < 4; ++mo)
#pragma unroll
        for (int nd = 0; nd < 2; ++nd) oacc[mo][nd] = (f32x4){0.f, 0.f, 0.f, 0.f};
#pragma unroll
      for (int mo = 0; mo < 4; ++mo) {
#pragma unroll
        for (int s = 0; s < 2; ++s) {
          u32 a0 = (u32)__shfl((int)pkk[mo][2 * s][0],     srcA, 64);
          u32 b0 = (u32)__shfl((int)pkk[mo][2 * s + 1][0], srcA, 64);
          u32 a1 = (u32)__shfl((int)pkk[mo][2 * s][1],     srcA, 64);
          u32 b1 = (u32)__shfl((int)pkk[mo][2 * s + 1][1], srcA, 64);
          u32 a2 = (u32)__shfl((int)pkk[mo][2 * s][0],     srcB, 64);
          u32 b2 = (u32)__shfl((int)pkk[mo][2 * s + 1][0], srcB, 64);
          u32 a3 = (u32)__shfl((int)pkk[mo][2 * s][1],     srcB, 64);
          u32 b3 = (u32)__shfl((int)pkk[mo][2 * s + 1][1], srcB, 64);
          union { u32 u[4]; s16x8 v; } pu;
          pu.u[0] = gh ? b0 : a0;
          pu.u[1] = gh ? b1 : a1;
          pu.u[2] = gh ? b2 : a2;
          pu.u[3] = gh ? b3 : a3;
          // swapped PV: row=d (V^T), col=q  -> packed attn-out stores
#pragma unroll
          for (int nd = 0; nd < 2; ++nd)
            oacc[mo][nd] = __builtin_amdgcn_mfma_f32_16x16x32_bf16(
                vb[nd][s], pu.v, oacc[mo][nd], 0, 0, 0);
        }
      }
      // epilogue: lane holds q=16mo+lr, d = h*32+nd*16+4lg+i  -> uint2 stores
#pragma unroll
      for (int mo = 0; mo < 4; ++mo) {
        const int q = 16 * mo + lr;
        if (q < NT) {
          const float invq = sINV[h * 64 + q];
#pragma unroll
          for (int nd = 0; nd < 2; ++nd) {
            uint2 pk;
            pk.x = (u32)f2bf(oacc[mo][nd][0] * invq) | ((u32)f2bf(oacc[mo][nd][1] * invq) << 16);
            pk.y = (u32)f2bf(oacc[mo][nd][2] * invq) | ((u32)f2bf(oacc[mo][nd][3] * invq) << 16);
            *(uint2*)&sX[q * SX_RS + h * 32 + nd * 16 + 4 * lg] = pk;
          }
        }
      }
    }
    __syncthreads();

    // ---- P4: proj via MFMA (weights cached in regs) + x prefetch ----
    {
      if (t + 1 < WPB) loadx(wbase + t + 1);
      f32x4 acc[2][4];
#pragma unroll
      for (int nt = 0; nt < 2; ++nt)
#pragma unroll
        for (int mt = 0; mt < 4; ++mt) acc[nt][mt] = (f32x4){0.f, 0.f, 0.f, 0.f};
#pragma unroll
      for (int kk = 0; kk < 8; ++kk) {
        s16x8 a[4];
#pragma unroll
        for (int mt = 0; mt < 4; ++mt)
          a[mt] = *(const s16x8*)&sX[(mt * 16 + lr) * SX_RS + kk * 32 + lg * 8];
#pragma unroll
        for (int nt = 0; nt < 2; ++nt)
#pragma unroll
          for (int mt = 0; mt < 4; ++mt)
            acc[nt][mt] = __builtin_amdgcn_mfma_f32_16x16x32_bf16(
                wpr[nt][kk], a[mt], acc[nt][mt], 0, 0, 0);
      }
      float* og = out + (size_t)wid * (NT * CD);
#pragma unroll
      for (int mt = 0; mt < 4; ++mt) {
        const int token = mt * 16 + lr;
        if (token < NT) {
#pragma unroll
          for (int nt = 0; nt < 2; ++nt) {
            float4 st;
            st.x = acc[nt][mt][0] + pb4[nt].x;
            st.y = acc[nt][mt][1] + pb4[nt].y;
            st.z = acc[nt][mt][2] + pb4[nt].z;
            st.w = acc[nt][mt][3] + pb4[nt].w;
            *(float4*)&og[token * CD + hh * 32 + nt * 16 + 4 * lg] = st;
          }
        }
      }
    }
    __syncthreads();

    if (t + 1 < WPB) storex();
    __syncthreads();
  }
}

extern "C" void kernel_launch(void* const* d_in, const int* in_sizes, int n_in,
                              void* d_out, int out_size, void* d_ws, size_t ws_size,
                              hipStream_t stream) {
  (void)in_sizes; (void)n_in; (void)out_size; (void)ws_size;
  const float* x           = (const float*)d_in[0];
  const float* qkv_w       = (const float*)d_in[1];
  const float* q_bias      = (const float*)d_in[2];
  const float* v_bias      = (const float*)d_in[3];
  const float* logit_scale = (const float*)d_in[4];
  const float* cpb_w1      = (const float*)d_in[5];
  const float* cpb_b1      = (const float*)d_in[6];
  const float* cpb_w2      = (const float*)d_in[7];
  const float* coords      = (const float*)d_in[8];
  const int*   rpi         = (const int*)d_in[9];
  const float* mask        = (const float*)d_in[10];
  const float* proj_w      = (const float*)d_in[11];
  const float* proj_b      = (const float*)d_in[12];
  float* out = (float*)d_out;

  float* table = (float*)d_ws;                        // 169*8 f32
  float* biasC = (float*)((char*)d_ws + WS_BIASC);    // 4*8*4096 f32 (512 KB)
  u16*   wq    = (u16*)((char*)d_ws + WS_WQKV);       // 384 KB bf16
  u16*   wp    = (u16*)((char*)d_ws + WS_WPROJ);      // 128 KB bf16

  hipLaunchKernelGGL(cpb_table_kernel, dim3(6), dim3(256), 0, stream,
                     coords, cpb_w1, cpb_b1, cpb_w2, table);
  hipLaunchKernelGGL(biasc_prep, dim3((4 * 8 * 4096 + 255) / 256), dim3(256),
                     0, stream, table, rpi, mask, biasC);
  hipLaunchKernelGGL(wcvt_kernel, dim3(128), dim3(256), 0, stream,
                     qkv_w, proj_w, wq, wp);
  hipLaunchKernelGGL(swin_fused, dim3(NBLK), dim3(512), 0, stream,
                     x, q_bias, v_bias, logit_scale, biasC,
                     wq, wp, proj_b, out);
}

// Round 4
// 634.669 us; speedup vs baseline: 1.4348x; 1.4348x over previous
//
#include <hip/hip_runtime.h>
#include <stdint.h>

typedef unsigned short u16;
typedef unsigned int u32;
typedef __attribute__((ext_vector_type(8))) short s16x8;   // 8 bf16 (4 VGPRs) MFMA frag
typedef __attribute__((ext_vector_type(4))) float f32x4;   // MFMA accum / vec4

// ---------- bf16 helpers ----------
__device__ __forceinline__ u16 f2bf(float f) {
  union { float f; u32 u; } v; v.f = f;
  u32 u = v.u;
  return (u16)((u + 0x7fffu + ((u >> 16) & 1u)) >> 16);
}
__device__ __forceinline__ float bf2f_lo(u32 u) {
  union { u32 uu; float f; } v; v.uu = u << 16; return v.f;
}
__device__ __forceinline__ float bf2f_hi(u32 u) {
  union { u32 uu; float f; } v; v.uu = u & 0xffff0000u; return v.f;
}
__device__ __forceinline__ void cvt8(uint4 w, float* f) {
  f[0] = bf2f_lo(w.x); f[1] = bf2f_hi(w.x);
  f[2] = bf2f_lo(w.y); f[3] = bf2f_hi(w.y);
  f[4] = bf2f_lo(w.z); f[5] = bf2f_hi(w.z);
  f[6] = bf2f_lo(w.w); f[7] = bf2f_hi(w.w);
}

// ---------- constants ----------
#define NT 49        // tokens per window
#define CD 256       // dim
#define NWIN 4096    // 64 imgs * 64 windows
#define SB_RS 520    // q|k bf16 row stride
#define SX_RS 264    // x / attn-out bf16 row stride
#define SVT_RS 72    // V^T kv stride

// LDS offsets (bytes)
#define L_SX  0                      // [64][264] bf16 = 33792
#define L_SB  33792                  // [64][520] bf16 = 66560
#define L_SVT 100352                 // [256][72] bf16 = 36864
#define L_SRQ 137216                 // [8][64] f32
#define L_SRK 139264                 // [8][64] f32
#define L_TOTAL 141312

// workspace offsets (bytes)
#define WS_BIASC 8192                 // 4*8*64*64 f32 = 524288
#define WS_WQKV  (8192 + 524288)      // 532480: 384 KB
#define WS_WPROJ (532480 + 393216)    // 925696: 128 KB

// =====================================================================
// Kernel A: CPB MLP: table[p*8+h]
// =====================================================================
__global__ void cpb_table_kernel(const float* __restrict__ coords,
                                 const float* __restrict__ w1,
                                 const float* __restrict__ b1,
                                 const float* __restrict__ w2,
                                 float* __restrict__ table) {
  int t = blockIdx.x * 256 + threadIdx.x;
  if (t >= 169 * 8) return;
  int p = t >> 3, h = t & 7;
  float c0 = coords[p * 2], c1 = coords[p * 2 + 1];
  float acc = 0.f;
  for (int j = 0; j < 512; ++j) {
    float hid = fmaf(c0, w1[j * 2], fmaf(c1, w1[j * 2 + 1], b1[j]));
    hid = fmaxf(hid, 0.f);
    acc = fmaf(hid, w2[h * 512 + j], acc);
  }
  table[t] = acc;
}

// =====================================================================
// Kernel B: combined bias table, 4 mask types (interior/right/bottom/corner)
//   biasC[t][h][q][kv] = rpb(h,q,kv) + mask[type_rep(t)][q][kv]; pads -> -1e9
// =====================================================================
__global__ void biasc_prep(const float* __restrict__ table,
                           const int* __restrict__ rpi,
                           const float* __restrict__ mask,
                           float* __restrict__ biasC) {
  int idx = blockIdx.x * 256 + threadIdx.x;
  if (idx >= 4 * 8 * 4096) return;
  int t = idx >> 15;
  int h = (idx >> 12) & 7;
  int q = (idx >> 6) & 63;
  int kv = idx & 63;
  float v = -1e9f;
  if (q < 49 && kv < 49) {
    float tb = table[rpi[q * 49 + kv] * 8 + h];
    float rpb = 16.f / (1.f + __expf(-tb));
    int wimg = ((t & 2) ? 56 : 0) + ((t & 1) ? 7 : 0);
    v = rpb + mask[wimg * 2401 + q * 49 + kv];
  }
  biasC[idx] = v;
}

// =====================================================================
// Kernel C: weights f32 -> bf16, MFMA fragment order.
// frag[ntile][kk][lane][8]; value = W[nt*16+(l&15)][kk*32+(l>>4)*8+j]
// =====================================================================
__global__ void wcvt_kernel(const float* __restrict__ qkv_w,
                            const float* __restrict__ proj_w,
                            u16* __restrict__ wq, u16* __restrict__ wp) {
  int t = blockIdx.x * 256 + threadIdx.x;
  if (t >= 32768) return;
  const float* src; u16* dst; int idx;
  if (t < 24576) { idx = t; src = qkv_w; dst = wq + (size_t)idx * 8; }
  else           { idx = t - 24576; src = proj_w; dst = wp + (size_t)idx * 8; }
  int nt = idx >> 9, rem = idx & 511;
  int kk = rem >> 6, l = rem & 63;
  int n = nt * 16 + (l & 15);
  int k = kk * 32 + (l >> 4) * 8;
  const float4* s = (const float4*)(src + (size_t)n * 256 + k);
  float4 v0 = s[0], v1 = s[1];
  u32 w0 = (u32)f2bf(v0.x) | ((u32)f2bf(v0.y) << 16);
  u32 w1 = (u32)f2bf(v0.z) | ((u32)f2bf(v0.w) << 16);
  u32 w2 = (u32)f2bf(v1.x) | ((u32)f2bf(v1.y) << 16);
  u32 w3 = (u32)f2bf(v1.z) | ((u32)f2bf(v1.w) << 16);
  *(uint4*)dst = make_uint4(w0, w1, w2, w3);
}

// =====================================================================
// P2 body: qkv GEMM with explicit 2-deep B-frag prefetch.
// First V0 tiles are q/k (swapped mfma -> packed col stores), rest are v
// (unswapped -> V^T packed stores). V0: hh<5 -> 6, hh==5 -> 2, hh>=6 -> 0.
// =====================================================================
template<int V0>
__device__ __forceinline__ void p2_body(
    const u16* sX, u16* sB, u16* sVT, const u16* wqb,
    const float* __restrict__ q_bias, const float* __restrict__ v_bias,
    const int hh, const int lr, const int lg) {
  f32x4 acc[6][4];
#pragma unroll
  for (int nt = 0; nt < 6; ++nt)
#pragma unroll
    for (int mt = 0; mt < 4; ++mt) acc[nt][mt] = (f32x4){0.f, 0.f, 0.f, 0.f};
  s16x8 bcur[6], bnxt[6];
#pragma unroll
  for (int nt = 0; nt < 6; ++nt)
    bcur[nt] = *(const s16x8*)&wqb[(nt * 8 + 0) * 512];
#pragma unroll
  for (int kk = 0; kk < 8; ++kk) {
    if (kk < 7) {
#pragma unroll
      for (int nt = 0; nt < 6; ++nt)
        bnxt[nt] = *(const s16x8*)&wqb[(nt * 8 + kk + 1) * 512];
    }
    s16x8 a[4];
#pragma unroll
    for (int mt = 0; mt < 4; ++mt)
      a[mt] = *(const s16x8*)&sX[(mt * 16 + lr) * SX_RS + kk * 32 + lg * 8];
#pragma unroll
    for (int nt = 0; nt < 6; ++nt)
#pragma unroll
      for (int mt = 0; mt < 4; ++mt)
        acc[nt][mt] = (nt < V0)
            ? __builtin_amdgcn_mfma_f32_16x16x32_bf16(bcur[nt], a[mt], acc[nt][mt], 0, 0, 0)
            : __builtin_amdgcn_mfma_f32_16x16x32_bf16(a[mt], bcur[nt], acc[nt][mt], 0, 0, 0);
#pragma unroll
    for (int nt = 0; nt < 6; ++nt) bcur[nt] = bnxt[nt];
  }
#pragma unroll
  for (int nt = 0; nt < 6; ++nt) {
    const int n0 = hh * 96 + nt * 16;
    if (nt < V0) {
      // q/k swapped: lane holds token=16mt+lr, 4 consecutive cols (n0&255)+4lg+i
      const int r = n0 >> 8;               // 0=q, 1=k (wave-uniform)
      const int cb = (n0 & 255) + 4 * lg;
      float4 bq = make_float4(0.f, 0.f, 0.f, 0.f);
      if (r == 0) bq = *(const float4*)(q_bias + cb);
      const int coff = (r << 8) + cb;
#pragma unroll
      for (int mt = 0; mt < 4; ++mt) {
        const int token = mt * 16 + lr;
        if (token < NT) {
          uint2 pk;
          pk.x = (u32)f2bf(acc[nt][mt][0] + bq.x) | ((u32)f2bf(acc[nt][mt][1] + bq.y) << 16);
          pk.y = (u32)f2bf(acc[nt][mt][2] + bq.z) | ((u32)f2bf(acc[nt][mt][3] + bq.w) << 16);
          *(uint2*)&sB[token * SB_RS + coff] = pk;
        }
      }
    } else {
      // v unswapped: lane holds col d=(n0&255)+lr, rows token=16mt+4lg+i
      const int c0 = (n0 & 255) + lr;
      const float bv = v_bias[c0];
      u16* vtb = &sVT[c0 * SVT_RS];
#pragma unroll
      for (int mt = 0; mt < 4; ++mt) {
        const int row0 = mt * 16 + lg * 4;
        float v0 = acc[nt][mt][0] + bv, v1 = acc[nt][mt][1] + bv;
        float v2 = acc[nt][mt][2] + bv, v3 = acc[nt][mt][3] + bv;
        if (mt < 3) {
          uint2 pk2;
          pk2.x = (u32)f2bf(v0) | ((u32)f2bf(v1) << 16);
          pk2.y = (u32)f2bf(v2) | ((u32)f2bf(v3) << 16);
          *(uint2*)&vtb[row0] = pk2;
        } else {
          if (row0     < NT) vtb[row0]     = f2bf(v0);
          if (row0 + 1 < NT) vtb[row0 + 1] = f2bf(v1);
          if (row0 + 2 < NT) vtb[row0 + 2] = f2bf(v2);
          if (row0 + 3 < NT) vtb[row0 + 3] = f2bf(v3);
        }
      }
    }
  }
}

// =====================================================================
// Fused per-window kernel (4096 blocks x 512 threads = 8 waves):
//   P1 x->LDS bf16 (loads issued first) ; P2 qkv MFMA (2-deep B prefetch) ;
//   P3 attention MFMA (no P3a barrier, reg 1/sum) ; P4 proj MFMA.
// =====================================================================
__global__ __launch_bounds__(512, 2) void swin_fused(
    const float* __restrict__ x,
    const float* __restrict__ q_bias, const float* __restrict__ v_bias,
    const float* __restrict__ logit_scale, const float* __restrict__ biasC,
    const u16* __restrict__ wq, const u16* __restrict__ wp,
    const float* __restrict__ proj_b,
    float* __restrict__ out) {
  __shared__ __attribute__((aligned(16))) unsigned char smem[L_TOTAL];
  u16*   sX  = (u16*)(smem + L_SX);
  u16*   sB  = (u16*)(smem + L_SB);
  u16*   sVT = (u16*)(smem + L_SVT);
  float* sRQ = (float*)(smem + L_SRQ);
  float* sRK = (float*)(smem + L_SRK);

  const int tid = threadIdx.x;
  const int wid = blockIdx.x;
  const int wimg = wid & 63;
  const int hh = tid >> 6;   // wave / head
  const int il = tid & 63;   // lane
  const int lr = il & 15;
  const int lg = il >> 4;

  // ---- P1: issue x loads FIRST, overlap setup under their latency ----
  float4 xr[6]; float4 xr6;
  {
    const float4* xg = (const float4*)(x + (size_t)wid * (NT * CD));
#pragma unroll
    for (int i = 0; i < 6; ++i) xr[i] = xg[tid + 512 * i];
    if (tid < 64) xr6 = xg[3072 + tid];
  }
  const float scl = __expf(fminf(logit_scale[hh], 4.605170186f));
  {
    u32* zx = (u32*)&sX[49 * SX_RS];     // 15*264/2
    for (int e = tid; e < 1980; e += 512) zx[e] = 0;
    u32* zb = (u32*)&sB[49 * SB_RS];     // 15*520/2
    for (int e = tid; e < 3900; e += 512) zb[e] = 0;
    u32* zv = (u32*)sVT;                 // 256*72/2
    for (int e = tid; e < 9216; e += 512) zv[e] = 0;
  }
  {
#pragma unroll
    for (int i = 0; i < 6; ++i) {
      const int e = tid + 512 * i;
      const int row = e >> 6, c4 = e & 63;
      float4 v = xr[i];
      u32 w0 = (u32)f2bf(v.x) | ((u32)f2bf(v.y) << 16);
      u32 w1 = (u32)f2bf(v.z) | ((u32)f2bf(v.w) << 16);
      *(uint2*)&sX[row * SX_RS + c4 * 4] = make_uint2(w0, w1);
    }
    if (tid < 64) {
      const int e = 3072 + tid;
      const int row = e >> 6, c4 = e & 63;
      float4 v = xr6;
      u32 w0 = (u32)f2bf(v.x) | ((u32)f2bf(v.y) << 16);
      u32 w1 = (u32)f2bf(v.z) | ((u32)f2bf(v.w) << 16);
      *(uint2*)&sX[row * SX_RS + c4 * 4] = make_uint2(w0, w1);
    }
  }
  __syncthreads();

  // ---- P2: qkv via MFMA ----
  {
    const u16* wqb = wq + (size_t)hh * 24576 + il * 8;
    if (hh < 5)       p2_body<6>(sX, sB, sVT, wqb, q_bias, v_bias, hh, lr, lg);
    else if (hh == 5) p2_body<2>(sX, sB, sVT, wqb, q_bias, v_bias, hh, lr, lg);
    else              p2_body<0>(sX, sB, sVT, wqb, q_bias, v_bias, hh, lr, lg);
  }
  __syncthreads();

  // ---- P3a: per-row inverse norms (wave-local: NO barrier needed) ----
  {
    float rqs = 0.f, rkv = 0.f;
    if (il < NT) {
      const uint4* qb4 = (const uint4*)&sB[il * SB_RS + hh * 32];
      const uint4* kb4 = (const uint4*)&sB[il * SB_RS + 256 + hh * 32];
      const int rot = (il >> 3) & 3;
      float f[8];
      float sq = 1e-6f, sk = 1e-6f;
#pragma unroll
      for (int c = 0; c < 4; ++c) {
        const int cg = (c + rot) & 3;
        cvt8(qb4[cg], f);
#pragma unroll
        for (int j = 0; j < 8; ++j) sq = fmaf(f[j], f[j], sq);
      }
#pragma unroll
      for (int c = 0; c < 4; ++c) {
        const int cg = (c + rot) & 3;
        cvt8(kb4[cg], f);
#pragma unroll
        for (int j = 0; j < 8; ++j) sk = fmaf(f[j], f[j], sk);
      }
      rqs = rsqrtf(sq) * scl;
      rkv = rsqrtf(sk);
    }
    sRQ[hh * 64 + il] = rqs;   // pad rows -> 0
    sRK[hh * 64 + il] = rkv;
    // same-wave producer->consumer: drain LDS writes before reads below
    asm volatile("s_waitcnt lgkmcnt(0)" ::: "memory");
    __builtin_amdgcn_sched_barrier(0);
  }

  // ---- P3b/c: S^T MFMA -> softmax (reg inv) -> PV MFMA (swapped) ----
  {
    const int h = hh;
    const int type = (((wimg >> 3) == 7) ? 2 : 0) | (((wimg & 7) == 7) ? 1 : 0);
    const float* bp = biasC + ((size_t)(type * 8 + h) << 12);
    f32x4 bias[4][4];
#pragma unroll
    for (int nt = 0; nt < 4; ++nt)
#pragma unroll
      for (int mt = 0; mt < 4; ++mt)
        bias[nt][mt] = *(const f32x4*)(bp + (lr + 16 * nt) * 64 + 16 * mt + 4 * lg);
    // S^T = mfma(k, q): row=kv, col=q
    s16x8 ka[4], qb[4];
#pragma unroll
    for (int mt = 0; mt < 4; ++mt)
      ka[mt] = *(const s16x8*)&sB[(lr + 16 * mt) * SB_RS + 256 + h * 32 + lg * 8];
#pragma unroll
    for (int nt = 0; nt < 4; ++nt)
      qb[nt] = *(const s16x8*)&sB[(lr + 16 * nt) * SB_RS + h * 32 + lg * 8];
    f32x4 sacc[4][4];
#pragma unroll
    for (int nt = 0; nt < 4; ++nt)
#pragma unroll
      for (int mt = 0; mt < 4; ++mt)
        sacc[nt][mt] = __builtin_amdgcn_mfma_f32_16x16x32_bf16(
            ka[mt], qb[nt], (f32x4){0.f, 0.f, 0.f, 0.f}, 0, 0, 0);
    f32x4 rk4[4];
#pragma unroll
    for (int mt = 0; mt < 4; ++mt)
      rk4[mt] = *(const f32x4*)&sRK[h * 64 + 16 * mt + 4 * lg];
    float invv[4];
#pragma unroll
    for (int nt = 0; nt < 4; ++nt) {
      const float rq_ = sRQ[h * 64 + lr + 16 * nt];
      float mx = -3e38f;
#pragma unroll
      for (int mt = 0; mt < 4; ++mt)
#pragma unroll
        for (int i = 0; i < 4; ++i) {
          float tv = fmaf(sacc[nt][mt][i] * rk4[mt][i], rq_, bias[nt][mt][i]);
          sacc[nt][mt][i] = tv;
          mx = fmaxf(mx, tv);
        }
      mx = fmaxf(mx, __shfl_xor(mx, 16, 64));
      mx = fmaxf(mx, __shfl_xor(mx, 32, 64));
      float sm = 0.f;
#pragma unroll
      for (int mt = 0; mt < 4; ++mt)
#pragma unroll
        for (int i = 0; i < 4; ++i) {
          float e = __expf(sacc[nt][mt][i] - mx);
          sacc[nt][mt][i] = e;
          sm += e;
        }
      sm += __shfl_xor(sm, 16, 64);
      sm += __shfl_xor(sm, 32, 64);
      invv[nt] = 1.0f / sm;     // every lane holds inv for q = lr + 16*nt
    }
    // pack P to bf16 pairs
    u32 pkk[4][4][2];
#pragma unroll
    for (int nt = 0; nt < 4; ++nt)
#pragma unroll
      for (int mt = 0; mt < 4; ++mt) {
        pkk[nt][mt][0] = (u32)f2bf(sacc[nt][mt][0]) | ((u32)f2bf(sacc[nt][mt][1]) << 16);
        pkk[nt][mt][1] = (u32)f2bf(sacc[nt][mt][2]) | ((u32)f2bf(sacc[nt][mt][3]) << 16);
      }
    // V^T B-frags
    s16x8 vb[2][2];
#pragma unroll
    for (int nd = 0; nd < 2; ++nd)
#pragma unroll
      for (int s = 0; s < 2; ++s)
        vb[nd][s] = *(const s16x8*)&sVT[(h * 32 + nd * 16 + lr) * SVT_RS + lg * 8 + 32 * s];
    // redistribute P into A-frag order via shfl
    const int srcA = lr + ((il & 16) << 1);
    const int srcB = srcA + 16;
    const bool gh = (il & 32) != 0;
    f32x4 oacc[4][2];
#pragma unroll
    for (int mo = 0; mo < 4; ++mo)
#pragma unroll
      for (int nd = 0; nd < 2; ++nd) oacc[mo][nd] = (f32x4){0.f, 0.f, 0.f, 0.f};
#pragma unroll
    for (int mo = 0; mo < 4; ++mo) {
#pragma unroll
      for (int s = 0; s < 2; ++s) {
        u32 a0 = (u32)__shfl((int)pkk[mo][2 * s][0],     srcA, 64);
        u32 b0 = (u32)__shfl((int)pkk[mo][2 * s + 1][0], srcA, 64);
        u32 a1 = (u32)__shfl((int)pkk[mo][2 * s][1],     srcA, 64);
        u32 b1 = (u32)__shfl((int)pkk[mo][2 * s + 1][1], srcA, 64);
        u32 a2 = (u32)__shfl((int)pkk[mo][2 * s][0],     srcB, 64);
        u32 b2 = (u32)__shfl((int)pkk[mo][2 * s + 1][0], srcB, 64);
        u32 a3 = (u32)__shfl((int)pkk[mo][2 * s][1],     srcB, 64);
        u32 b3 = (u32)__shfl((int)pkk[mo][2 * s + 1][1], srcB, 64);
        union { u32 u[4]; s16x8 v; } pu;
        pu.u[0] = gh ? b0 : a0;
        pu.u[1] = gh ? b1 : a1;
        pu.u[2] = gh ? b2 : a2;
        pu.u[3] = gh ? b3 : a3;
        // swapped PV: row=d (V^T), col=q
#pragma unroll
        for (int nd = 0; nd < 2; ++nd)
          oacc[mo][nd] = __builtin_amdgcn_mfma_f32_16x16x32_bf16(
              vb[nd][s], pu.v, oacc[mo][nd], 0, 0, 0);
      }
    }
    // epilogue: lane holds q=16mo+lr, d = h*32+nd*16+4lg+i -> uint2 stores
#pragma unroll
    for (int mo = 0; mo < 4; ++mo) {
      const int q = 16 * mo + lr;
      if (q < NT) {
        const float invq = invv[mo];
#pragma unroll
        for (int nd = 0; nd < 2; ++nd) {
          uint2 pk;
          pk.x = (u32)f2bf(oacc[mo][nd][0] * invq) | ((u32)f2bf(oacc[mo][nd][1] * invq) << 16);
          pk.y = (u32)f2bf(oacc[mo][nd][2] * invq) | ((u32)f2bf(oacc[mo][nd][3] * invq) << 16);
          *(uint2*)&sX[q * SX_RS + h * 32 + nd * 16 + 4 * lg] = pk;
        }
      }
    }
  }
  // issue proj weight/bias loads here: latency hides under the barrier
  s16x8 wpr[2][8];
  {
    const u16* wpb = wp + (size_t)hh * 8192 + il * 8;
#pragma unroll
    for (int nt = 0; nt < 2; ++nt)
#pragma unroll
      for (int kk = 0; kk < 8; ++kk)
        wpr[nt][kk] = *(const s16x8*)&wpb[(nt * 8 + kk) * 512];
  }
  float4 pb4[2];
#pragma unroll
  for (int nt = 0; nt < 2; ++nt)
    pb4[nt] = *(const float4*)(proj_b + hh * 32 + nt * 16 + 4 * lg);
  __syncthreads();

  // ---- P4: proj via MFMA (swapped -> float4 global stores) ----
  {
    f32x4 acc[2][4];
#pragma unroll
    for (int nt = 0; nt < 2; ++nt)
#pragma unroll
      for (int mt = 0; mt < 4; ++mt) acc[nt][mt] = (f32x4){0.f, 0.f, 0.f, 0.f};
#pragma unroll
    for (int kk = 0; kk < 8; ++kk) {
      s16x8 a[4];
#pragma unroll
      for (int mt = 0; mt < 4; ++mt)
        a[mt] = *(const s16x8*)&sX[(mt * 16 + lr) * SX_RS + kk * 32 + lg * 8];
#pragma unroll
      for (int nt = 0; nt < 2; ++nt)
#pragma unroll
        for (int mt = 0; mt < 4; ++mt)
          acc[nt][mt] = __builtin_amdgcn_mfma_f32_16x16x32_bf16(
              wpr[nt][kk], a[mt], acc[nt][mt], 0, 0, 0);
    }
    float* og = out + (size_t)wid * (NT * CD);
#pragma unroll
    for (int mt = 0; mt < 4; ++mt) {
      const int token = mt * 16 + lr;
      if (token < NT) {
#pragma unroll
        for (int nt = 0; nt < 2; ++nt) {
          float4 st;
          st.x = acc[nt][mt][0] + pb4[nt].x;
          st.y = acc[nt][mt][1] + pb4[nt].y;
          st.z = acc[nt][mt][2] + pb4[nt].z;
          st.w = acc[nt][mt][3] + pb4[nt].w;
          *(float4*)&og[token * CD + hh * 32 + nt * 16 + 4 * lg] = st;
        }
      }
    }
  }
}

extern "C" void kernel_launch(void* const* d_in, const int* in_sizes, int n_in,
                              void* d_out, int out_size, void* d_ws, size_t ws_size,
                              hipStream_t stream) {
  (void)in_sizes; (void)n_in; (void)out_size; (void)ws_size;
  const float* x           = (const float*)d_in[0];
  const float* qkv_w       = (const float*)d_in[1];
  const float* q_bias      = (const float*)d_in[2];
  const float* v_bias      = (const float*)d_in[3];
  const float* logit_scale = (const float*)d_in[4];
  const float* cpb_w1      = (const float*)d_in[5];
  const float* cpb_b1      = (const float*)d_in[6];
  const float* cpb_w2      = (const float*)d_in[7];
  const float* coords      = (const float*)d_in[8];
  const int*   rpi         = (const int*)d_in[9];
  const float* mask        = (const float*)d_in[10];
  const float* proj_w      = (const float*)d_in[11];
  const float* proj_b      = (const float*)d_in[12];
  float* out = (float*)d_out;

  float* table = (float*)d_ws;                        // 169*8 f32
  float* biasC = (float*)((char*)d_ws + WS_BIASC);    // 4*8*4096 f32 (512 KB)
  u16*   wq    = (u16*)((char*)d_ws + WS_WQKV);       // 384 KB bf16
  u16*   wp    = (u16*)((char*)d_ws + WS_WPROJ);      // 128 KB bf16

  hipLaunchKernelGGL(cpb_table_kernel, dim3(6), dim3(256), 0, stream,
                     coords, cpb_w1, cpb_b1, cpb_w2, table);
  hipLaunchKernelGGL(biasc_prep, dim3((4 * 8 * 4096 + 255) / 256), dim3(256),
                     0, stream, table, rpi, mask, biasC);
  hipLaunchKernelGGL(wcvt_kernel, dim3(128), dim3(256), 0, stream,
                     qkv_w, proj_w, wq, wp);
  hipLaunchKernelGGL(swin_fused, dim3(NWIN), dim3(512), 0, stream,
                     x, q_bias, v_bias, logit_scale, biasC,
                     wq, wp, proj_b, out);
}